// Round 8
// baseline (104.923 us; speedup 1.0000x reference)
//
#include <hip/hip_runtime.h>
#include <stdint.h>

#define IN_F 2048
#define OUT_F 2048
#define N_ROWS 8192

// ---- GEMM geometry: 256x256 tile, BK=32, 8 waves (2Mx4N), 4-deep LDS,
// r2-structure (single barrier per K-step), 32x32x16 MFMA.
#define BM 256
#define BN 256
#define BK 32
#define NT (IN_F / BK)             // 64 K-steps
#define TM_TILES (N_ROWS / BM)     // 32
#define TN_TILES (OUT_F / BN)      // 8
#define NWG (TM_TILES * TN_TILES)  // 256 == #CUs
#define TILE_SHORTS (BM * BK)      // 8192 shorts = 16 KiB
#define BUF_SHORTS (2 * TILE_SHORTS)  // A+B = 32 KiB per buffer

typedef __bf16 bf16x8 __attribute__((ext_vector_type(8)));
typedef float f32x16 __attribute__((ext_vector_type(16)));
typedef unsigned short ushortx8 __attribute__((ext_vector_type(8)));

__device__ __forceinline__ unsigned short f2bf(float f) {
  unsigned u = __builtin_bit_cast(unsigned, f);
  u += 0x7FFFu + ((u >> 16) & 1u);
  return (unsigned short)(u >> 16);
}

__device__ __forceinline__ void async16(void* lds, const void* g) {
  __builtin_amdgcn_global_load_lds(
      (const __attribute__((address_space(1))) void*)(uintptr_t)g,
      (__attribute__((address_space(3))) void*)(uint32_t)(uintptr_t)lds,
      16, 0, 0);
}

__device__ __forceinline__ bf16x8 ld8(const unsigned short* p) {
  return __builtin_bit_cast(bf16x8, *reinterpret_cast<const ushortx8*>(p));
}

// ---- fused prep: blocks [0,8192) convert A fp32->bf16; [8192,10240) build Ht
__global__ __launch_bounds__(256) void k_prep(const float* __restrict__ A,
                                              unsigned short* __restrict__ Ab,
                                              const float* __restrict__ W,
                                              unsigned short* __restrict__ Ht) {
  const int bid = blockIdx.x;
  if (bid < 8192) {
    const size_t t = (size_t)bid * 256 + threadIdx.x;
    const float4* a4 = reinterpret_cast<const float4*>(A);
    float4 v0 = a4[2 * t];
    float4 v1 = a4[2 * t + 1];
    ushortx8 o;
    o[0] = f2bf(v0.x); o[1] = f2bf(v0.y); o[2] = f2bf(v0.z); o[3] = f2bf(v0.w);
    o[4] = f2bf(v1.x); o[5] = f2bf(v1.y); o[6] = f2bf(v1.z); o[7] = f2bf(v1.w);
    *reinterpret_cast<ushortx8*>(Ab + t * 8) = o;
  } else {
    // Ht[b][a] = H_perm[a][b] = s(q,c) * W[u][(q^c)*512 + v]
    const int t = (bid - 8192) * 256 + threadIdx.x;
    const int b = t >> 8;
    const int a0 = (t & 255) << 3;
    const int c = b & 3, v = b >> 2;
    ushortx8 o;
#pragma unroll
    for (int e = 0; e < 8; ++e) {
      const int a = a0 + e;
      const int q = a & 3, u = a >> 2;
      float w = W[(size_t)u * OUT_F + ((q ^ c) << 9) + v];
      if ((0x284E >> ((q << 2) | c)) & 1) w = -w;
      o[e] = f2bf(w);
    }
    *reinterpret_cast<ushortx8*>(Ht + (size_t)b * IN_F + a0) = o;
  }
}

// ---- main GEMM: C = A(bf16) @ Ht^T + bias (r2 structure, 32x32x16 MFMA) ----
__global__ __launch_bounds__(512, 2) void k_gemm(const unsigned short* __restrict__ A,
                                                 const unsigned short* __restrict__ Bt,
                                                 const float* __restrict__ bias,
                                                 float* __restrict__ C) {
  __shared__ __align__(16) unsigned short lds[4 * BUF_SHORTS];  // 128 KiB

  const int tid = threadIdx.x;
  const int lane = tid & 63;
  const int w = tid >> 6;     // wave 0..7
  const int wm = w >> 2;      // 0..1 -> rows wm*128..+128
  const int wn = w & 3;       // 0..3 -> cols wn*64..+64
  const int fr32 = lane & 31; // fragment row/col (32x32)
  const int half = lane >> 5; // k-half selector

  // XCD-bijective swizzle: 256 wgs, 32 contiguous tiles per XCD
  const int wg = blockIdx.x;
  const int swz = (wg & 7) * (NWG >> 3) + (wg >> 3);
  const int tm = swz >> 3;
  const int tn = swz & 7;
  const int row0 = tm * BM, col0 = tn * BN;

  // ---- staging (r2-verified): chunk t in [0,1024): row r=t>>2, slot s=t&3;
  // write-side swizzle: slot s holds k-group ga = s ^ ((r>>1)&3)
  // (pre-swizzled GLOBAL source, linear LDS dest).
  const unsigned short* srcA[2];
  const unsigned short* srcB[2];
  int tOff[2];
#pragma unroll
  for (int i = 0; i < 2; ++i) {
    const int t = w * 128 + i * 64 + lane;
    const int r = t >> 2, s = t & 3;
    const int ga = s ^ ((r >> 1) & 3);
    srcA[i] = A + (size_t)(row0 + r) * IN_F + ga * 8;
    srcB[i] = Bt + (size_t)(col0 + r) * IN_F + ga * 8;
    tOff[i] = t * 8;  // shorts
  }

#define STAGE(T)                                              \
  do {                                                        \
    unsigned short* base_ = &lds[((T) & 3) * BUF_SHORTS];     \
    const int ko_ = (T) * BK;                                 \
    async16(base_ + tOff[0], srcA[0] + ko_);                  \
    async16(base_ + tOff[1], srcA[1] + ko_);                  \
    async16(base_ + TILE_SHORTS + tOff[0], srcB[0] + ko_);    \
    async16(base_ + TILE_SHORTS + tOff[1], srcB[1] + ko_);    \
  } while (0)

  // ---- fragment read offsets (shorts). 32x32x16 operand layout:
  // lane l supplies row/col = l&31, k-elems [16*kh + 8*(l>>5), +8).
  // k-8-group gk = 2*kh + half; read-side swizzle slot = gk ^ ((r>>1)&3).
  int offA32[4][2], offB32[2][2];
#pragma unroll
  for (int mi = 0; mi < 4; ++mi) {
    const int r = wm * 128 + mi * 32 + fr32;
#pragma unroll
    for (int kh = 0; kh < 2; ++kh) {
      const int gk = 2 * kh + half;
      offA32[mi][kh] = r * BK + ((gk ^ ((r >> 1) & 3)) << 3);
    }
  }
#pragma unroll
  for (int ni = 0; ni < 2; ++ni) {
    const int r = wn * 64 + ni * 32 + fr32;
#pragma unroll
    for (int kh = 0; kh < 2; ++kh) {
      const int gk = 2 * kh + half;
      offB32[ni][kh] = TILE_SHORTS + r * BK + ((gk ^ ((r >> 1) & 3)) << 3);
    }
  }

  f32x16 acc[4][2] = {};

#define MFMA32_(a_, b_, c_) \
  __builtin_amdgcn_mfma_f32_32x32x16_bf16(a_, b_, c_, 0, 0, 0)

  // prologue: 3 tiles in flight (12 loads/wave)
  STAGE(0);
  STAGE(1);
  STAGE(2);

  // Per K-step (r2 structure): vmcnt(N) -> barrier -> 12 ds_reads ->
  // STAGE(T+3) -> 16 MFMA. One barrier per K-step.
#define TILE(T, VMSTR, DOSTAGE)                                               \
  do {                                                                        \
    asm volatile("s_waitcnt vmcnt(" VMSTR ")" ::: "memory");                  \
    __builtin_amdgcn_s_barrier();                                             \
    __builtin_amdgcn_sched_barrier(0);                                        \
    const unsigned short* b_ = &lds[((T) & 3) * BUF_SHORTS];                  \
    bf16x8 bf[2][2], af[4][2];                                                \
    _Pragma("unroll") for (int ni = 0; ni < 2; ++ni)                          \
      _Pragma("unroll") for (int kh = 0; kh < 2; ++kh)                        \
        bf[ni][kh] = ld8(b_ + offB32[ni][kh]);                                \
    _Pragma("unroll") for (int mi = 0; mi < 4; ++mi)                          \
      _Pragma("unroll") for (int kh = 0; kh < 2; ++kh)                        \
        af[mi][kh] = ld8(b_ + offA32[mi][kh]);                                \
    if (DOSTAGE) STAGE((T) + 3);                                              \
    __builtin_amdgcn_s_setprio(1);                                            \
    _Pragma("unroll") for (int kh = 0; kh < 2; ++kh)                          \
      _Pragma("unroll") for (int mi = 0; mi < 4; ++mi)                        \
        _Pragma("unroll") for (int ni = 0; ni < 2; ++ni)                      \
          acc[mi][ni] = MFMA32_(af[mi][kh], bf[ni][kh], acc[mi][ni]);         \
    __builtin_amdgcn_s_setprio(0);                                            \
  } while (0)

#pragma unroll 1
  for (int t = 0; t < NT - 3; ++t) {
    TILE(t, "8", true);
  }
  TILE(NT - 3, "8", false);
  TILE(NT - 2, "4", false);
  TILE(NT - 1, "0", false);

#undef TILE
#undef STAGE

  // ---- epilogue: 32x32 C/D layout: col=lane&31,
  // row = (reg&3) + 8*(reg>>2) + 4*(lane>>5)  (guide, m74/m101-verified)
  float bv[2];
#pragma unroll
  for (int ni = 0; ni < 2; ++ni) bv[ni] = bias[col0 + wn * 64 + ni * 32 + fr32];
#pragma unroll
  for (int mi = 0; mi < 4; ++mi) {
#pragma unroll
    for (int ni = 0; ni < 2; ++ni) {
#pragma unroll
      for (int reg = 0; reg < 16; ++reg) {
        const int row = row0 + wm * 128 + mi * 32 + (reg & 3) + 8 * (reg >> 2) + 4 * half;
        const int col = col0 + wn * 64 + ni * 32 + fr32;
        C[(size_t)row * OUT_F + col] = acc[mi][ni][reg] + bv[ni];
      }
    }
  }
}

// ---- fallback if workspace too small: naive fp32 ----
__global__ __launch_bounds__(256) void k_naive(const float* __restrict__ A,
                                               const float* __restrict__ W,
                                               const float* __restrict__ bias,
                                               float* __restrict__ C) {
  const int idx = blockIdx.x * 256 + threadIdx.x;
  const int m = idx >> 11;
  const int b = idx & (OUT_F - 1);
  const int c = b & 3, v = b >> 2;
  float acc = 0.f;
  const float* arow = A + (size_t)m * IN_F;
  for (int a = 0; a < IN_F; ++a) {
    const int q = a & 3, u = a >> 2;
    float h = W[(size_t)u * OUT_F + ((q ^ c) << 9) + v];
    if ((0x284E >> ((q << 2) | c)) & 1) h = -h;
    acc += arow[a] * h;
  }
  C[idx] = acc + bias[b];
}

extern "C" void kernel_launch(void* const* d_in, const int* in_sizes, int n_in,
                              void* d_out, int out_size, void* d_ws, size_t ws_size,
                              hipStream_t stream) {
  (void)in_sizes; (void)n_in; (void)out_size;
  const float* inp  = (const float*)d_in[0];
  const float* w    = (const float*)d_in[1];
  const float* bias = (const float*)d_in[2];
  float* out = (float*)d_out;

  const size_t needA = (size_t)N_ROWS * IN_F * sizeof(unsigned short);  // 32 MiB
  const size_t needH = (size_t)IN_F * OUT_F * sizeof(unsigned short);   //  8 MiB
  if (ws_size < needA + needH) {
    k_naive<<<(N_ROWS * OUT_F) / 256, 256, 0, stream>>>(inp, w, bias, out);
    return;
  }

  unsigned short* Ab = (unsigned short*)d_ws;
  unsigned short* Ht = Ab + (size_t)N_ROWS * IN_F;

  k_prep<<<8192 + 2048, 256, 0, stream>>>(inp, Ab, w, Ht);
  k_gemm<<<NWG, 512, 0, stream>>>(Ab, Ht, bias, out);
}